// Round 4
// baseline (162.310 us; speedup 1.0000x reference)
//
#include <hip/hip_runtime.h>
#include <hip/hip_bf16.h>
#include <math.h>

#define BATCH   8192
#define NFIELD  24
#define FAC     16
#define PAIRS   276
#define HID     64
#define PG      6
#define PPG     (PAIRS / PG)   // 46 pairs per group
#define NBB     (BATCH / 64)   // 128 batch blocks of 64 rows

typedef __attribute__((ext_vector_type(8))) __bf16 bf16x8;
typedef __attribute__((ext_vector_type(4))) float f32x4;

// ---- workspace layout (bytes) ----
// xvT:   [128][24][2][64][8] bf16              = 6,291,456
// combo: [276 + 2 pad][4608]                    = 1,281,024
//        per pair: [0,256) b1R f32x4; [256,512) w2R f32x4; [512,4608) W1 frags
// partial:[PG][8192] f32                        =   196,608
// consts: [1] f32 (b[0] + sum b2)
#define XVT_OFF   0
#define COMBO_OFF 6291456
#define PART_OFF  (COMBO_OFF + 1281024)
#define CONST_OFF (PART_OFF + 196608)

// Fused prep: blocks [0,768) gather v->xvT; blocks [768,837) repack weights.
__global__ void prep_all(const int* __restrict__ inputs,
                         const float* __restrict__ v,
                         const float* __restrict__ W1,
                         const float* __restrict__ W2,
                         const float* __restrict__ b1,
                         const float* __restrict__ b2,
                         const float* __restrict__ bsc,
                         __hip_bfloat16* __restrict__ xvT,
                         char* __restrict__ combo,
                         float* __restrict__ consts) {
    __shared__ float red[256];
    int blk = blockIdx.x;
    if (blk < 768) {
        int t = blk * 256 + threadIdx.x;          // < 196608
        int field = t >> 13;
        int b = t & 8191;
        int idx = inputs[b * NFIELD + field];
        const float4* src = (const float4*)(v + (long)idx * FAC);
        union { __hip_bfloat16 h[16]; uint4 u[2]; } tmp;
        float4 a0 = src[0], a1 = src[1], a2 = src[2], a3 = src[3];
        tmp.h[0]  = __float2bfloat16(a0.x); tmp.h[1]  = __float2bfloat16(a0.y);
        tmp.h[2]  = __float2bfloat16(a0.z); tmp.h[3]  = __float2bfloat16(a0.w);
        tmp.h[4]  = __float2bfloat16(a1.x); tmp.h[5]  = __float2bfloat16(a1.y);
        tmp.h[6]  = __float2bfloat16(a1.z); tmp.h[7]  = __float2bfloat16(a1.w);
        tmp.h[8]  = __float2bfloat16(a2.x); tmp.h[9]  = __float2bfloat16(a2.y);
        tmp.h[10] = __float2bfloat16(a2.z); tmp.h[11] = __float2bfloat16(a2.w);
        tmp.h[12] = __float2bfloat16(a3.x); tmp.h[13] = __float2bfloat16(a3.y);
        tmp.h[14] = __float2bfloat16(a3.z); tmp.h[15] = __float2bfloat16(a3.w);
        int bb = b >> 6, row = b & 63;
        __hip_bfloat16* base = xvT + (long)bb * 24576 + field * 1024 + row * 8;
        *(uint4*)base         = tmp.u[0];
        *(uint4*)(base + 512) = tmp.u[1];
    } else {
        int wb = blk - 768;                        // 0..68
        int t = wb * 256 + threadIdx.x;            // < 17664
        int p = t >> 6;
        int L = t & 63;
        int q = L >> 4, c = L & 15;
        char* base = combo + (long)p * 4608;
        union { __hip_bfloat16 h[8]; uint4 u; } buf;
#pragma unroll
        for (int tt = 0; tt < 4; ++tt) {
#pragma unroll
            for (int jj = 0; jj < 8; ++jj)
                buf.h[jj] = __float2bfloat16(W1[p * 2048 + (q * 8 + jj) * 64 + tt * 16 + c]);
            *(uint4*)(base + 512 + tt * 1024 + L * 16) = buf.u;
        }
        if (L < 16) {
            float4 bv = {b1[p * 64 + L], b1[p * 64 + 16 + L], b1[p * 64 + 32 + L], b1[p * 64 + 48 + L]};
            *(float4*)(base + L * 16) = bv;
            float4 wv = {W2[p * 64 + L], W2[p * 64 + 16 + L], W2[p * 64 + 32 + L], W2[p * 64 + 48 + L]};
            *(float4*)(base + 256 + L * 16) = wv;
        }
        if (wb == 1) {   // zero the 2 pad pairs (depth-2 tail prefetch reads them)
            uint4 z = {0, 0, 0, 0};
            for (int k = threadIdx.x; k < 576; k += 256)
                *(uint4*)(combo + (long)PAIRS * 4608 + k * 16) = z;
        }
        if (wb == 0) {
            float s = 0.f;
            for (int k = threadIdx.x; k < PAIRS; k += 256) s += b2[k];
            red[threadIdx.x] = s;
            __syncthreads();
            for (int off = 128; off > 0; off >>= 1) {
                if (threadIdx.x < off) red[threadIdx.x] += red[threadIdx.x + off];
                __syncthreads();
            }
            if (threadIdx.x == 0) consts[0] = red[0] + bsc[0];
        }
    }
}

// 512-thread blocks: 8 waves share one 64-row slab; waves 0-3 -> pg 2g (row
// slices 0-3), waves 4-7 -> pg 2g+1. Barrier-free K-loop, depth-2 register
// prefetch of the per-pair weight package from L2/L3.
#define LOADSET(MB1, MW2, F0, F1, F2, F3, PTR)        \
    MB1 = *(const float4*)((PTR) + mcol);             \
    MW2 = *(const float4*)((PTR) + 256 + mcol);       \
    F0  = *(const bf16x8*)((PTR) + 512  + l16);       \
    F1  = *(const bf16x8*)((PTR) + 1536 + l16);       \
    F2  = *(const bf16x8*)((PTR) + 2560 + l16);       \
    F3  = *(const bf16x8*)((PTR) + 3584 + l16);

#define COMPUTE(MB1, MW2, F0, F1, F2, F3)                                    \
    {                                                                        \
        int fso = ((quad < 2) ? i : j) * 1088;                               \
        bf16x8 af = *(const bf16x8*)(xv_s + fso + arow);                     \
        f32x4 c0 = {MB1.x, MB1.x, MB1.x, MB1.x};                             \
        f32x4 c1 = {MB1.y, MB1.y, MB1.y, MB1.y};                             \
        f32x4 c2 = {MB1.z, MB1.z, MB1.z, MB1.z};                             \
        f32x4 c3 = {MB1.w, MB1.w, MB1.w, MB1.w};                             \
        c0 = __builtin_amdgcn_mfma_f32_16x16x32_bf16(af, F0, c0, 0, 0, 0);   \
        c1 = __builtin_amdgcn_mfma_f32_16x16x32_bf16(af, F1, c1, 0, 0, 0);   \
        c2 = __builtin_amdgcn_mfma_f32_16x16x32_bf16(af, F2, c2, 0, 0, 0);   \
        c3 = __builtin_amdgcn_mfma_f32_16x16x32_bf16(af, F3, c3, 0, 0, 0);   \
        a0 = fmaf(fmaxf(c0[0], 0.f), MW2.x, a0);                             \
        a1 = fmaf(fmaxf(c0[1], 0.f), MW2.x, a1);                             \
        a2 = fmaf(fmaxf(c0[2], 0.f), MW2.x, a2);                             \
        a3 = fmaf(fmaxf(c0[3], 0.f), MW2.x, a3);                             \
        a0 = fmaf(fmaxf(c1[0], 0.f), MW2.y, a0);                             \
        a1 = fmaf(fmaxf(c1[1], 0.f), MW2.y, a1);                             \
        a2 = fmaf(fmaxf(c1[2], 0.f), MW2.y, a2);                             \
        a3 = fmaf(fmaxf(c1[3], 0.f), MW2.y, a3);                             \
        a0 = fmaf(fmaxf(c2[0], 0.f), MW2.z, a0);                             \
        a1 = fmaf(fmaxf(c2[1], 0.f), MW2.z, a1);                             \
        a2 = fmaf(fmaxf(c2[2], 0.f), MW2.z, a2);                             \
        a3 = fmaf(fmaxf(c2[3], 0.f), MW2.z, a3);                             \
        a0 = fmaf(fmaxf(c3[0], 0.f), MW2.w, a0);                             \
        a1 = fmaf(fmaxf(c3[1], 0.f), MW2.w, a1);                             \
        a2 = fmaf(fmaxf(c3[2], 0.f), MW2.w, a2);                             \
        a3 = fmaf(fmaxf(c3[3], 0.f), MW2.w, a3);                             \
        ++j;                                                                 \
        if (j == NFIELD) { ++i; j = i + 1; }                                 \
    }

__global__ __launch_bounds__(512, 4) void ffm_main(
        const __hip_bfloat16* __restrict__ xvT,
        const char* __restrict__ combo,
        float* __restrict__ partial) {
    // [field][half][row64][8] with +32 elem (64B) pad per 512-elem half-group
    __shared__ __align__(16) __hip_bfloat16 xv_s[24 * 1088];  // 51 KB

    int tid  = threadIdx.x;
    int bb   = blockIdx.x & (NBB - 1);
    int bkpg = blockIdx.x >> 7;          // 0..2
    int lane = tid & 63;
    int wave = tid >> 6;                 // 0..7
    int col  = lane & 15;
    int quad = lane >> 4;
    int h    = wave >> 2;                // pg half within block
    int r    = wave & 3;                 // 16-row slice

    // stage 48KB slab: 3072 16B chunks, swizzle ch -> elem ch*8 + (ch>>6)*32
    {
        const uint4* src = (const uint4*)(xvT + (long)bb * 24576);
#pragma unroll
        for (int it = 0; it < 6; ++it) {
            int ch = tid + it * 512;
            *(uint4*)(xv_s + ch * 8 + (ch >> 6) * 32) = src[ch];
        }
    }
    __syncthreads();

    int pg = bkpg * 2 + h;               // 0..5
    int p0 = pg * PPG;
    int i = 0, rem = p0;
    while (rem >= NFIELD - 1 - i) { rem -= NFIELD - 1 - i; ++i; }
    int j = i + 1 + rem;

    const int arow = (quad & 1) * 544 + (r * 16 + col) * 8;
    const int mcol = col * 16;
    const int l16  = lane * 16;
    const char* wp = combo + (long)p0 * 4608;

    float4 mb1a, mw2a, mb1b, mw2b;
    bf16x8 fa0, fa1, fa2, fa3, fb0, fb1, fb2, fb3;
    LOADSET(mb1a, mw2a, fa0, fa1, fa2, fa3, wp)
    LOADSET(mb1b, mw2b, fb0, fb1, fb2, fb3, wp + 4608)

    float a0 = 0.f, a1 = 0.f, a2 = 0.f, a3 = 0.f;

    for (int k = 0; k < PPG; k += 2) {
        COMPUTE(mb1a, mw2a, fa0, fa1, fa2, fa3)
        LOADSET(mb1a, mw2a, fa0, fa1, fa2, fa3, wp + 2 * 4608)
        COMPUTE(mb1b, mw2b, fb0, fb1, fb2, fb3)
        LOADSET(mb1b, mw2b, fb0, fb1, fb2, fb3, wp + 3 * 4608)
        wp += 2 * 4608;
    }

    // reduce over the 16 column-lanes within each quad group
#pragma unroll
    for (int m = 1; m < 16; m <<= 1) {
        a0 += __shfl_xor(a0, m, 64);
        a1 += __shfl_xor(a1, m, 64);
        a2 += __shfl_xor(a2, m, 64);
        a3 += __shfl_xor(a3, m, 64);
    }
    if (col == 0) {
        f32x4 o; o[0] = a0; o[1] = a1; o[2] = a2; o[3] = a3;
        *(f32x4*)&partial[pg * BATCH + bb * 64 + r * 16 + quad * 4] = o;
    }
}

__global__ void finalize(const int* __restrict__ inputs,
                         const float* __restrict__ w,
                         const float* __restrict__ consts,
                         const float* __restrict__ partial,
                         float* __restrict__ out) {
    int bidx = blockIdx.x * 256 + threadIdx.x;   // < 8192
    const int4* ip = (const int4*)(inputs + bidx * NFIELD);
    float l = 0.f;
#pragma unroll
    for (int q = 0; q < 6; ++q) {
        int4 v4 = ip[q];
        l += w[v4.x] + w[v4.y] + w[v4.z] + w[v4.w];
    }
    float s = l + consts[0];
#pragma unroll
    for (int g = 0; g < PG; ++g) s += partial[g * BATCH + bidx];
    out[bidx] = 1.0f / (1.0f + expf(-s));
}

extern "C" void kernel_launch(void* const* d_in, const int* in_sizes, int n_in,
                              void* d_out, int out_size, void* d_ws, size_t ws_size,
                              hipStream_t stream) {
    const int*   inputs = (const int*)d_in[0];
    const float* w      = (const float*)d_in[1];
    const float* v      = (const float*)d_in[2];
    const float* bsc    = (const float*)d_in[3];
    const float* W1     = (const float*)d_in[4];
    const float* b1     = (const float*)d_in[5];
    const float* W2     = (const float*)d_in[6];
    const float* b2     = (const float*)d_in[7];
    float* out = (float*)d_out;

    char* ws = (char*)d_ws;
    __hip_bfloat16* xvT = (__hip_bfloat16*)(ws + XVT_OFF);
    char*  combo   = ws + COMBO_OFF;
    float* partial = (float*)(ws + PART_OFF);
    float* consts  = (float*)(ws + CONST_OFF);

    prep_all<<<768 + 69, 256, 0, stream>>>(inputs, v, W1, W2, b1, b2, bsc, xvT, combo, consts);
    ffm_main<<<NBB * 3, 512, 0, stream>>>(xvT, combo, partial);
    finalize<<<BATCH / 256, 256, 0, stream>>>(inputs, w, consts, partial, out);
}

// Round 5
// 150.267 us; speedup vs baseline: 1.0801x; 1.0801x over previous
//
#include <hip/hip_runtime.h>
#include <hip/hip_bf16.h>
#include <math.h>

#define BATCH   8192
#define NFIELD  24
#define FAC     16
#define PAIRS   276
#define HID     64
#define NSETS   24             // 23 real 12-pair sets + 1 idle set
#define SETLEN  12
#define NBB     (BATCH / 64)   // 128 batch blocks of 64 rows

typedef __attribute__((ext_vector_type(8))) __bf16 bf16x8;
typedef __attribute__((ext_vector_type(4))) float f32x4;

// ---- workspace layout (bytes) ----
// xvT:   [128][24][2][64][8] bf16              = 6,291,456
// combo: [276 + 3 pad][4608]                    = 1,285,632
// partial:[24][8192] f32                        =   786,432
// consts: [1] f32
#define XVT_OFF   0
#define COMBO_OFF 6291456
#define PART_OFF  (COMBO_OFF + 1285632)
#define CONST_OFF (PART_OFF + 786432)

// Fused prep: blocks [0,768) gather v->xvT; blocks [768,837) repack weights.
__global__ void prep_all(const int* __restrict__ inputs,
                         const float* __restrict__ v,
                         const float* __restrict__ W1,
                         const float* __restrict__ W2,
                         const float* __restrict__ b1,
                         const float* __restrict__ b2,
                         const float* __restrict__ bsc,
                         __hip_bfloat16* __restrict__ xvT,
                         char* __restrict__ combo,
                         float* __restrict__ consts) {
    __shared__ float red[256];
    int blk = blockIdx.x;
    if (blk < 768) {
        int t = blk * 256 + threadIdx.x;          // < 196608
        int field = t >> 13;
        int b = t & 8191;
        int idx = inputs[b * NFIELD + field];
        const float4* src = (const float4*)(v + (long)idx * FAC);
        union { __hip_bfloat16 h[16]; uint4 u[2]; } tmp;
        float4 a0 = src[0], a1 = src[1], a2 = src[2], a3 = src[3];
        tmp.h[0]  = __float2bfloat16(a0.x); tmp.h[1]  = __float2bfloat16(a0.y);
        tmp.h[2]  = __float2bfloat16(a0.z); tmp.h[3]  = __float2bfloat16(a0.w);
        tmp.h[4]  = __float2bfloat16(a1.x); tmp.h[5]  = __float2bfloat16(a1.y);
        tmp.h[6]  = __float2bfloat16(a1.z); tmp.h[7]  = __float2bfloat16(a1.w);
        tmp.h[8]  = __float2bfloat16(a2.x); tmp.h[9]  = __float2bfloat16(a2.y);
        tmp.h[10] = __float2bfloat16(a2.z); tmp.h[11] = __float2bfloat16(a2.w);
        tmp.h[12] = __float2bfloat16(a3.x); tmp.h[13] = __float2bfloat16(a3.y);
        tmp.h[14] = __float2bfloat16(a3.z); tmp.h[15] = __float2bfloat16(a3.w);
        int bb = b >> 6, row = b & 63;
        __hip_bfloat16* base = xvT + (long)bb * 24576 + field * 1024 + row * 8;
        *(uint4*)base         = tmp.u[0];
        *(uint4*)(base + 512) = tmp.u[1];
    } else {
        int wb = blk - 768;                        // 0..68
        int t = wb * 256 + threadIdx.x;            // < 17664
        int p = t >> 6;
        int L = t & 63;
        int q = L >> 4, c = L & 15;
        char* base = combo + (long)p * 4608;
        union { __hip_bfloat16 h[8]; uint4 u; } buf;
#pragma unroll
        for (int tt = 0; tt < 4; ++tt) {
#pragma unroll
            for (int jj = 0; jj < 8; ++jj)
                buf.h[jj] = __float2bfloat16(W1[p * 2048 + (q * 8 + jj) * 64 + tt * 16 + c]);
            *(uint4*)(base + 512 + tt * 1024 + L * 16) = buf.u;
        }
        if (L < 16) {
            float4 bv = {b1[p * 64 + L], b1[p * 64 + 16 + L], b1[p * 64 + 32 + L], b1[p * 64 + 48 + L]};
            *(float4*)(base + L * 16) = bv;
            float4 wv = {W2[p * 64 + L], W2[p * 64 + 16 + L], W2[p * 64 + 32 + L], W2[p * 64 + 48 + L]};
            *(float4*)(base + 256 + L * 16) = wv;
        }
        if (wb == 1) {   // zero the 3 pad pairs (zero weights are mathematically inert)
            uint4 z = {0, 0, 0, 0};
            for (int k = threadIdx.x; k < 864; k += 256)
                *(uint4*)(combo + (long)PAIRS * 4608 + k * 16) = z;
        }
        if (wb == 0) {
            float s = 0.f;
            for (int k = threadIdx.x; k < PAIRS; k += 256) s += b2[k];
            red[threadIdx.x] = s;
            __syncthreads();
            for (int off = 128; off > 0; off >>= 1) {
                if (threadIdx.x < off) red[threadIdx.x] += red[threadIdx.x + off];
                __syncthreads();
            }
            if (threadIdx.x == 0) consts[0] = red[0] + bsc[0];
        }
    }
}

// 256-thread blocks, 64-row slab in LDS shared by 4 waves. Each wave owns a
// DISTINCT 12-pair set (ws = pg*4+wave) and applies each weight package to
// all 4 row-tiles (16 MFMAs per package) -> 4x less L2 weight traffic.
// Barrier-free K-loop, depth-1 register prefetch.
__global__ __launch_bounds__(256, 4) void ffm_main(
        const __hip_bfloat16* __restrict__ xvT,
        const char* __restrict__ combo,
        float* __restrict__ partial) {
    // [field][half][row64][8] with +32 elem (64B) pad per 512-elem half-group
    __shared__ __align__(16) __hip_bfloat16 xv_s[24 * 1088];  // 51 KB

    int tid  = threadIdx.x;
    int bb   = blockIdx.x & (NBB - 1);
    int pg   = blockIdx.x >> 7;          // 0..5
    int lane = tid & 63;
    int wave = tid >> 6;
    int col  = lane & 15;
    int quad = lane >> 4;

    // stage 48KB slab: 3072 16B chunks, swizzle ch -> elem ch*8 + (ch>>6)*32
    {
        const uint4* src = (const uint4*)(xvT + (long)bb * 24576);
#pragma unroll
        for (int it = 0; it < 12; ++it) {
            int ch = tid + it * 256;
            *(uint4*)(xv_s + ch * 8 + (ch >> 6) * 32) = src[ch];
        }
    }
    __syncthreads();

    int ws = pg * 4 + wave;              // 0..23; set 23 is idle (pad pairs)
    float acc[16];
#pragma unroll
    for (int r = 0; r < 16; ++r) acc[r] = 0.f;

    const int abase = (quad & 1) * 544 + col * 8;   // + t*128 per row-tile
    const int mcol  = col * 16;
    const int l16   = lane * 16;

    if (ws < 23) {
        int p0 = ws * SETLEN;
        int i = 0, rem = p0;
        while (rem >= NFIELD - 1 - i) { rem -= NFIELD - 1 - i; ++i; }
        int j = i + 1 + rem;

        const char* wp = combo + (long)p0 * 4608;
        float4 mb1 = *(const float4*)(wp + mcol);
        float4 mw2 = *(const float4*)(wp + 256 + mcol);
        bf16x8 f0 = *(const bf16x8*)(wp + 512 + l16);
        bf16x8 f1 = *(const bf16x8*)(wp + 1536 + l16);
        bf16x8 f2 = *(const bf16x8*)(wp + 2560 + l16);
        bf16x8 f3 = *(const bf16x8*)(wp + 3584 + l16);

#pragma unroll 2
        for (int k = 0; k < SETLEN; ++k) {
            // depth-1 prefetch of next package (last iter reads zeroed pad)
            const char* wn = wp + 4608;
            float4 nb1 = *(const float4*)(wn + mcol);
            float4 nw2 = *(const float4*)(wn + 256 + mcol);
            bf16x8 nf0 = *(const bf16x8*)(wn + 512 + l16);
            bf16x8 nf1 = *(const bf16x8*)(wn + 1536 + l16);
            bf16x8 nf2 = *(const bf16x8*)(wn + 2560 + l16);
            bf16x8 nf3 = *(const bf16x8*)(wn + 3584 + l16);

            int fso = ((quad < 2) ? i : j) * 1088;
#pragma unroll
            for (int t = 0; t < 4; ++t) {
                bf16x8 af = *(const bf16x8*)(xv_s + fso + abase + t * 128);
                f32x4 c0 = {mb1.x, mb1.x, mb1.x, mb1.x};
                f32x4 c1 = {mb1.y, mb1.y, mb1.y, mb1.y};
                f32x4 c2 = {mb1.z, mb1.z, mb1.z, mb1.z};
                f32x4 c3 = {mb1.w, mb1.w, mb1.w, mb1.w};
                c0 = __builtin_amdgcn_mfma_f32_16x16x32_bf16(af, f0, c0, 0, 0, 0);
                c1 = __builtin_amdgcn_mfma_f32_16x16x32_bf16(af, f1, c1, 0, 0, 0);
                c2 = __builtin_amdgcn_mfma_f32_16x16x32_bf16(af, f2, c2, 0, 0, 0);
                c3 = __builtin_amdgcn_mfma_f32_16x16x32_bf16(af, f3, c3, 0, 0, 0);
#pragma unroll
                for (int r = 0; r < 4; ++r) {
                    acc[t * 4 + r] = fmaf(fmaxf(c0[r], 0.f), mw2.x, acc[t * 4 + r]);
                    acc[t * 4 + r] = fmaf(fmaxf(c1[r], 0.f), mw2.y, acc[t * 4 + r]);
                    acc[t * 4 + r] = fmaf(fmaxf(c2[r], 0.f), mw2.z, acc[t * 4 + r]);
                    acc[t * 4 + r] = fmaf(fmaxf(c3[r], 0.f), mw2.w, acc[t * 4 + r]);
                }
            }
            mb1 = nb1; mw2 = nw2; f0 = nf0; f1 = nf1; f2 = nf2; f3 = nf3;
            wp = wn;
            ++j;
            if (j == NFIELD) { ++i; j = i + 1; }
        }
    }

    // reduce each acc over the 16 column-lanes within its quad group
#pragma unroll
    for (int m = 1; m < 16; m <<= 1) {
#pragma unroll
        for (int r = 0; r < 16; ++r) acc[r] += __shfl_xor(acc[r], m, 64);
    }
    if (col == 0) {
#pragma unroll
        for (int t = 0; t < 4; ++t) {
            f32x4 o; o[0] = acc[t*4+0]; o[1] = acc[t*4+1]; o[2] = acc[t*4+2]; o[3] = acc[t*4+3];
            *(f32x4*)&partial[ws * BATCH + bb * 64 + t * 16 + quad * 4] = o;
        }
    }
}

__global__ void finalize(const int* __restrict__ inputs,
                         const float* __restrict__ w,
                         const float* __restrict__ consts,
                         const float* __restrict__ partial,
                         float* __restrict__ out) {
    int bidx = blockIdx.x * 256 + threadIdx.x;   // < 8192
    const int4* ip = (const int4*)(inputs + bidx * NFIELD);
    float l = 0.f;
#pragma unroll
    for (int q = 0; q < 6; ++q) {
        int4 v4 = ip[q];
        l += w[v4.x] + w[v4.y] + w[v4.z] + w[v4.w];
    }
    float s = l + consts[0];
#pragma unroll
    for (int g = 0; g < NSETS; ++g) s += partial[g * BATCH + bidx];
    out[bidx] = 1.0f / (1.0f + expf(-s));
}

extern "C" void kernel_launch(void* const* d_in, const int* in_sizes, int n_in,
                              void* d_out, int out_size, void* d_ws, size_t ws_size,
                              hipStream_t stream) {
    const int*   inputs = (const int*)d_in[0];
    const float* w      = (const float*)d_in[1];
    const float* v      = (const float*)d_in[2];
    const float* bsc    = (const float*)d_in[3];
    const float* W1     = (const float*)d_in[4];
    const float* b1     = (const float*)d_in[5];
    const float* W2     = (const float*)d_in[6];
    const float* b2     = (const float*)d_in[7];
    float* out = (float*)d_out;

    char* ws = (char*)d_ws;
    __hip_bfloat16* xvT = (__hip_bfloat16*)(ws + XVT_OFF);
    char*  combo   = ws + COMBO_OFF;
    float* partial = (float*)(ws + PART_OFF);
    float* consts  = (float*)(ws + CONST_OFF);

    prep_all<<<768 + 69, 256, 0, stream>>>(inputs, v, W1, W2, b1, b2, bsc, xvT, combo, consts);
    ffm_main<<<NBB * 6, 256, 0, stream>>>(xvT, combo, partial);
    finalize<<<BATCH / 256, 256, 0, stream>>>(inputs, w, consts, partial, out);
}